// Round 4
// baseline (16193.684 us; speedup 1.0000x reference)
//
#include <hip/hip_runtime.h>
#include <hip/hip_bf16.h>

// Problem constants
#define BATCH 1024
#define SEQ   350
#define LAT   512
#define VOC   41
#define H0D   512
#define H1D   256
#define H2D   128
#define H3D   32
#define G1    768   // 3*H1D
#define G2    384   // 3*H2D
#define G3    96    // 3*H3D
#define SOS   1

// ws layout (floats)
#define O_HH0   0         // wt_hh0 [256][768]
#define O_IH1   196608    // wt_ih1 [256][384]
#define O_HH1   294912    // wt_hh1 [128][384]
#define O_IH2   344064    // wt_ih2 [128][96]
#define O_HH2   356352    // wt_hh2 [32][96]
#define O_PROJ  359424    // wt_proj [32][41]
#define O_TAB   360736    // gi0 table [41][768]
#define WS_FLOATS 392224

#define RT 4    // batch rows per block
#define NT 512  // threads per block (8 waves)

__global__ void setup_kernel(const float* __restrict__ Whh0, const float* __restrict__ Wih1,
                             const float* __restrict__ Whh1, const float* __restrict__ Wih2,
                             const float* __restrict__ Whh2, const float* __restrict__ Wproj,
                             const float* __restrict__ Wemb, const float* __restrict__ bemb,
                             const float* __restrict__ Wih0, const float* __restrict__ bih0,
                             float* __restrict__ ws) {
  int idx = blockIdx.x * blockDim.x + threadIdx.x;
  if (idx < 196608) { int o = idx % G1, k = idx / G1; ws[O_HH0 + k*G1 + o] = Whh0[o*H1D + k]; return; }
  idx -= 196608;
  if (idx < 98304)  { int o = idx % G2, k = idx / G2; ws[O_IH1 + k*G2 + o] = Wih1[o*H1D + k]; return; }
  idx -= 98304;
  if (idx < 49152)  { int o = idx % G2, k = idx / G2; ws[O_HH1 + k*G2 + o] = Whh1[o*H2D + k]; return; }
  idx -= 49152;
  if (idx < 12288)  { int o = idx % G3, k = idx / G3; ws[O_IH2 + k*G3 + o] = Wih2[o*H2D + k]; return; }
  idx -= 12288;
  if (idx < 3072)   { int o = idx % G3, k = idx / G3; ws[O_HH2 + k*G3 + o] = Whh2[o*H3D + k]; return; }
  idx -= 3072;
  if (idx < 1312)   { int o = idx % VOC, k = idx / VOC; ws[O_PROJ + k*VOC + o] = Wproj[o*H3D + k]; return; }
  idx -= 1312;
  if (idx < 31488) {
    // gi0 table: exact (f64-accumulated) x@Wih0.T + bih0 per token value.
    int o = idx % G1, v = idx / G1;
    double acc = (double)bih0[o];
    const float* wrow = Wih0 + (size_t)o * H0D;
    for (int k = 0; k < H0D; ++k)
      acc += ((double)Wemb[k*VOC + v] + (double)bemb[k]) * (double)wrow[k];
    ws[O_TAB + v*G1 + o] = (float)acc;
  }
}

__device__ __forceinline__ double sigmd(double x) { return 1.0 / (1.0 + exp(-x)); }

// Union LDS views (lifetimes separated by barriers; audited per-pair)
#define SCA(kh,r,g,j)   scU[((((kh)*RT+(r))*3+(g))<<8) + (j)]   // [2][RT][3][256]
#define SCB(sg,r,g,jb)  scU[((((sg)*RT+(r))*3+(g))<<7) + (jb)]  // [4][RT][3][128]
#define SCC(sc,g,r,jc)  scU[((((sc)*3+(g))*RT+(r))<<5) + (jc)]  // [10][3][RT][32]

__global__ __launch_bounds__(NT, 2) void gru_persist(
    const float* __restrict__ latent, const int* __restrict__ tgt,
    const float* __restrict__ Winit, const float* __restrict__ binit,
    const float* __restrict__ bhh0,
    const float* __restrict__ bih1, const float* __restrict__ bhh1,
    const float* __restrict__ bih2, const float* __restrict__ bhh2,
    const float* __restrict__ bproj,
    const float* __restrict__ ws, float* __restrict__ out)
{
  const int tid = threadIdx.x;
  const int r0 = blockIdx.x * RT;

  const float* wt_hh0 = ws + O_HH0;
  const float* wt_ih1 = ws + O_IH1;
  const float* wt_hh1 = ws + O_HH1;
  const float* wt_ih2 = ws + O_IH2;
  const float* wt_hh2 = ws + O_HH2;
  const float* wt_proj = ws + O_PROJ;
  const float* tab = ws + O_TAB;

  float* __restrict__ out_logits = out;
  float* __restrict__ out_pred = out + (size_t)BATCH * SEQ * VOC;

  __shared__ float scU[6144];             // 24 KB union: scA / scB / scC
  __shared__ float h0s[RT][H1D];          // 4 KB
  __shared__ float h1s[RT][H2D];          // 2 KB
  __shared__ float h2s[RT][H3D];          // 0.5 KB
  __shared__ float sc_log[RT][VOC];
  __shared__ int toks[RT];

  // ---- init hidden states: combined = latent @ Winit.T + binit (f64 accumulate, one-time)
  for (int idx = tid; idx < RT * 416; idx += NT) {
    int r = idx / 416, jj = idx - r * 416;
    const float* lrow = latent + (size_t)(r0 + r) * LAT;
    const float* wrow = Winit + (size_t)jj * LAT;
    double acc = (double)binit[jj];
    for (int k = 0; k < LAT; ++k) acc += (double)lrow[k] * (double)wrow[k];
    float a = (float)acc;
    if (jj < H1D) h0s[r][jj] = a;
    else if (jj < H1D + H2D) h1s[r][jj - H1D] = a;
    else h2s[r][jj - H1D - H2D] = a;
  }
  __syncthreads();

  for (int t = 0; t < SEQ; ++t) {
    if (tid < RT) toks[tid] = (t == 0) ? SOS : tgt[(size_t)(r0 + tid) * SEQ + t];

    // ======== Stage A: GRU0 gh. j = tid&255, K=256 split by kh = tid>>8 ========
    // Dot products: chunks of 8 in f32, carried in f64 per chunk.
    const int j = tid & 255;
    const int kh = tid >> 8;
    {
      double acc[3][RT];
      #pragma unroll
      for (int g3 = 0; g3 < 3; ++g3)
        #pragma unroll
        for (int r = 0; r < RT; ++r) acc[g3][r] = 0.0;
      const float* __restrict__ wbase = wt_hh0 + j;
      const int k0 = kh * 128;
      for (int kb = k0; kb < k0 + 128; kb += 8) {
        float hc[RT][8];
        #pragma unroll
        for (int r = 0; r < RT; ++r) {
          *(float4*)&hc[r][0] = *(const float4*)&h0s[r][kb];
          *(float4*)&hc[r][4] = *(const float4*)&h0s[r][kb + 4];
        }
        float f[3][RT];
        #pragma unroll
        for (int g3 = 0; g3 < 3; ++g3)
          #pragma unroll
          for (int r = 0; r < RT; ++r) f[g3][r] = 0.f;
        #pragma unroll
        for (int u = 0; u < 8; ++u) {
          const float* wp = wbase + (size_t)(kb + u) * G1;
          float w0 = wp[0], w1 = wp[256], w2 = wp[512];
          #pragma unroll
          for (int r = 0; r < RT; ++r) {
            f[0][r] = fmaf(hc[r][u], w0, f[0][r]);
            f[1][r] = fmaf(hc[r][u], w1, f[1][r]);
            f[2][r] = fmaf(hc[r][u], w2, f[2][r]);
          }
        }
        #pragma unroll
        for (int g3 = 0; g3 < 3; ++g3)
          #pragma unroll
          for (int r = 0; r < RT; ++r) acc[g3][r] += (double)f[g3][r];
      }
      #pragma unroll
      for (int r = 0; r < RT; ++r) {
        SCA(kh, r, 0, j) = (float)acc[0][r];
        SCA(kh, r, 1, j) = (float)acc[1][r];
        SCA(kh, r, 2, j) = (float)acc[2][r];
      }
    }
    __syncthreads();  // B1: scA partials + toks visible; all h0s dot-reads done
    {
      // pointwise split: kh half owns rows {2kh, 2kh+1}
      const double bR = (double)bhh0[j], bZ = (double)bhh0[256 + j], bN = (double)bhh0[512 + j];
      #pragma unroll
      for (int rr = 0; rr < 2; ++rr) {
        const int r = kh * 2 + rr;
        const float* trow = tab + (size_t)toks[r] * G1;
        double gR = (double)trow[j] + (double)SCA(0, r, 0, j) + (double)SCA(1, r, 0, j) + bR;
        double gZ = (double)trow[256 + j] + (double)SCA(0, r, 1, j) + (double)SCA(1, r, 1, j) + bZ;
        double giN = (double)trow[512 + j];
        double ghN = (double)SCA(0, r, 2, j) + (double)SCA(1, r, 2, j) + bN;
        double rg = sigmd(gR);
        double zg = sigmd(gZ);
        double ng = tanh(fma(rg, ghN, giN));
        // own (r,j) old read then write: only this thread touches h0s[r][j]
        h0s[r][j] = (float)((1.0 - zg) * ng + zg * (double)h0s[r][j]);
      }
    }
    __syncthreads();  // B2: h0s new visible; scA free

    // ======== Stage B: GRU1. jb=tid&127; g=tid>>7: g0,g1 = gi1 K-halves (new h0s),
    //                                               g2,g3 = gh1 K-halves (old h1s) ========
    const int jb = tid & 127;
    const int g = tid >> 7;
    {
      double acc[3][RT];
      #pragma unroll
      for (int g3 = 0; g3 < 3; ++g3)
        #pragma unroll
        for (int r = 0; r < RT; ++r) acc[g3][r] = 0.0;
      const float* __restrict__ wbase = (g < 2) ? (wt_ih1 + jb) : (wt_hh1 + jb);
      const float (* __restrict__ hsrc)[RT > 0 ? H1D : 1];
      const int k0 = (g < 2) ? g * 128 : (g - 2) * 64;
      const int kn = (g < 2) ? 128 : 64;
      for (int kb = k0; kb < k0 + kn; kb += 8) {
        float hc[RT][8];
        if (g < 2) {
          #pragma unroll
          for (int r = 0; r < RT; ++r) {
            *(float4*)&hc[r][0] = *(const float4*)&h0s[r][kb];
            *(float4*)&hc[r][4] = *(const float4*)&h0s[r][kb + 4];
          }
        } else {
          #pragma unroll
          for (int r = 0; r < RT; ++r) {
            *(float4*)&hc[r][0] = *(const float4*)&h1s[r][kb];
            *(float4*)&hc[r][4] = *(const float4*)&h1s[r][kb + 4];
          }
        }
        float f[3][RT];
        #pragma unroll
        for (int g3 = 0; g3 < 3; ++g3)
          #pragma unroll
          for (int r = 0; r < RT; ++r) f[g3][r] = 0.f;
        #pragma unroll
        for (int u = 0; u < 8; ++u) {
          const float* wp = wbase + (size_t)(kb + u) * G2;
          float w0 = wp[0], w1 = wp[128], w2 = wp[256];
          #pragma unroll
          for (int r = 0; r < RT; ++r) {
            f[0][r] = fmaf(hc[r][u], w0, f[0][r]);
            f[1][r] = fmaf(hc[r][u], w1, f[1][r]);
            f[2][r] = fmaf(hc[r][u], w2, f[2][r]);
          }
        }
        #pragma unroll
        for (int g3 = 0; g3 < 3; ++g3)
          #pragma unroll
          for (int r = 0; r < RT; ++r) acc[g3][r] += (double)f[g3][r];
      }
      #pragma unroll
      for (int r = 0; r < RT; ++r) {
        SCB(g, r, 0, jb) = (float)acc[0][r];
        SCB(g, r, 1, jb) = (float)acc[1][r];
        SCB(g, r, 2, jb) = (float)acc[2][r];
      }
    }
    __syncthreads();  // B3: scB partials visible; all h0s/h1s dot-reads done
    {
      // pointwise: group g owns row r=g
      const int r = g;
      const double biR = (double)bih1[jb], biZ = (double)bih1[128 + jb], biN = (double)bih1[256 + jb];
      const double bhR = (double)bhh1[jb], bhZ = (double)bhh1[128 + jb], bhN = (double)bhh1[256 + jb];
      double giR = (double)SCB(0, r, 0, jb) + (double)SCB(1, r, 0, jb) + biR;
      double giZ = (double)SCB(0, r, 1, jb) + (double)SCB(1, r, 1, jb) + biZ;
      double giN = (double)SCB(0, r, 2, jb) + (double)SCB(1, r, 2, jb) + biN;
      double ghR = (double)SCB(2, r, 0, jb) + (double)SCB(3, r, 0, jb) + bhR;
      double ghZ = (double)SCB(2, r, 1, jb) + (double)SCB(3, r, 1, jb) + bhZ;
      double ghN = (double)SCB(2, r, 2, jb) + (double)SCB(3, r, 2, jb) + bhN;
      double rg = sigmd(giR + ghR);
      double zg = sigmd(giZ + ghZ);
      double ng = tanh(fma(rg, ghN, giN));
      h1s[r][jb] = (float)((1.0 - zg) * ng + zg * (double)h1s[r][jb]);
    }
    __syncthreads();  // B4: h1s new visible; scB free

    // ======== Stage C: GRU2. jc=tid&31; sc=tid>>5: sc0..7 = gi2 K-slices of 16 (new h1s),
    //                                               sc8,9 = gh2 K-slices of 16 (old h2s) ========
    const int jc = tid & 31;
    const int sc = tid >> 5;  // 0..15
    {
      float f[3][RT];
      #pragma unroll
      for (int g3 = 0; g3 < 3; ++g3)
        #pragma unroll
        for (int r = 0; r < RT; ++r) f[g3][r] = 0.f;
      if (sc < 8) {
        for (int kk = 0; kk < 16; ++kk) {
          int k = sc * 16 + kk;
          const float* wp = wt_ih2 + (size_t)k * G3;
          float w0 = wp[jc], w1 = wp[32 + jc], w2 = wp[64 + jc];
          #pragma unroll
          for (int r = 0; r < RT; ++r) {
            float hval = h1s[r][k];
            f[0][r] = fmaf(hval, w0, f[0][r]);
            f[1][r] = fmaf(hval, w1, f[1][r]);
            f[2][r] = fmaf(hval, w2, f[2][r]);
          }
        }
      } else if (sc < 10) {
        for (int kk = 0; kk < 16; ++kk) {
          int k = (sc - 8) * 16 + kk;
          const float* wp = wt_hh2 + (size_t)k * G3;
          float w0 = wp[jc], w1 = wp[32 + jc], w2 = wp[64 + jc];
          #pragma unroll
          for (int r = 0; r < RT; ++r) {
            float hval = h2s[r][k];
            f[0][r] = fmaf(hval, w0, f[0][r]);
            f[1][r] = fmaf(hval, w1, f[1][r]);
            f[2][r] = fmaf(hval, w2, f[2][r]);
          }
        }
      }
      if (sc < 10) {
        #pragma unroll
        for (int r = 0; r < RT; ++r) {
          SCC(sc, 0, r, jc) = f[0][r];
          SCC(sc, 1, r, jc) = f[1][r];
          SCC(sc, 2, r, jc) = f[2][r];
        }
      }
    }
    __syncthreads();  // B5: scC partials visible; all h1s/h2s dot-reads done
    if (tid < 128) {
      int r = tid >> 5, jj = tid & 31;
      double giR = (double)bih2[jj], giZ = (double)bih2[32 + jj], giN = (double)bih2[64 + jj];
      #pragma unroll
      for (int s = 0; s < 8; ++s) {
        giR += (double)SCC(s, 0, r, jj);
        giZ += (double)SCC(s, 1, r, jj);
        giN += (double)SCC(s, 2, r, jj);
      }
      double ghR = (double)SCC(8, 0, r, jj) + (double)SCC(9, 0, r, jj) + (double)bhh2[jj];
      double ghZ = (double)SCC(8, 1, r, jj) + (double)SCC(9, 1, r, jj) + (double)bhh2[32 + jj];
      double ghN = (double)SCC(8, 2, r, jj) + (double)SCC(9, 2, r, jj) + (double)bhh2[64 + jj];
      double rg = sigmd(giR + ghR);
      double zg = sigmd(giZ + ghZ);
      double ng = tanh(fma(rg, ghN, giN));
      h2s[r][jj] = (float)((1.0 - zg) * ng + zg * (double)h2s[r][jj]);
    }
    __syncthreads();  // B6: h2s new visible; scC free

    // ======== Stage D: projection + argmax ========
    if (tid < RT * VOC) {
      int r = tid / VOC, c = tid - r * VOC;
      double acc = (double)bproj[c];
      #pragma unroll
      for (int k = 0; k < H3D; ++k)
        acc = fma((double)h2s[r][k], (double)wt_proj[k * VOC + c], acc);
      float accf = (float)acc;
      out_logits[((size_t)(r0 + r) * SEQ + t) * VOC + c] = accf;
      sc_log[r][c] = accf;
    }
    __syncthreads();  // B7: logits visible
    if (tid < RT) {
      float best = sc_log[tid][0];
      int bi = 0;
      #pragma unroll
      for (int c = 1; c < VOC; ++c) {
        float v = sc_log[tid][c];
        if (v > best) { best = v; bi = c; }
      }
      out_pred[(size_t)(r0 + tid) * SEQ + t] = (float)bi;
    }
    // Hazard audit (union scU): A-read(after B1) vs B-write(after B2): B2.
    // B-read(after B3) vs C-write(after B4): B4. C-read(after B5) vs next
    // A-write(after B7): B6,B7. sc_log is outside the union (read after B7
    // concurrent with next A-writes).
  }
}

extern "C" void kernel_launch(void* const* d_in, const int* in_sizes, int n_in,
                              void* d_out, int out_size, void* d_ws, size_t ws_size,
                              hipStream_t stream) {
  const float* latent  = (const float*)d_in[0];
  const int*   tgt     = (const int*)d_in[1];
  const float* Wemb    = (const float*)d_in[2];
  const float* bemb    = (const float*)d_in[3];
  const float* Winit   = (const float*)d_in[4];
  const float* binit   = (const float*)d_in[5];
  const float* Wih0    = (const float*)d_in[6];
  const float* Whh0    = (const float*)d_in[7];
  const float* bih0    = (const float*)d_in[8];
  const float* bhh0    = (const float*)d_in[9];
  const float* Wih1    = (const float*)d_in[10];
  const float* Whh1    = (const float*)d_in[11];
  const float* bih1    = (const float*)d_in[12];
  const float* bhh1    = (const float*)d_in[13];
  const float* Wih2    = (const float*)d_in[14];
  const float* Whh2    = (const float*)d_in[15];
  const float* bih2    = (const float*)d_in[16];
  const float* bhh2    = (const float*)d_in[17];
  const float* Wproj   = (const float*)d_in[18];
  const float* bproj   = (const float*)d_in[19];

  float* ws = (float*)d_ws;
  float* out = (float*)d_out;

  int setup_threads = WS_FLOATS;
  int setup_blocks = (setup_threads + 255) / 256;
  setup_kernel<<<setup_blocks, 256, 0, stream>>>(Whh0, Wih1, Whh1, Wih2, Whh2, Wproj,
                                                Wemb, bemb, Wih0, bih0, ws);

  gru_persist<<<BATCH / RT, NT, 0, stream>>>(latent, tgt, Winit, binit,
                                             bhh0, bih1, bhh1, bih2, bhh2, bproj,
                                             ws, out);
}

// Round 5
// 12848.836 us; speedup vs baseline: 1.2603x; 1.2603x over previous
//
#include <hip/hip_runtime.h>
#include <hip/hip_bf16.h>

// Problem constants
#define BATCH 1024
#define SEQ   350
#define LAT   512
#define VOC   41
#define H0D   512
#define H1D   256
#define H2D   128
#define H3D   32
#define G1    768   // 3*H1D
#define G2    384   // 3*H2D
#define G3    96    // 3*H3D
#define SOS   1

// ws layout (floats)
#define O_HH0   0         // wt_hh0 [256][768]
#define O_IH1   196608    // wt_ih1 [256][384]
#define O_HH1   294912    // wt_hh1 [128][384]
#define O_IH2   344064    // wt_ih2 [128][96]
#define O_HH2   356352    // wt_hh2 [32][96]
#define O_PROJ  359424    // wt_proj [32][41]
#define O_TAB   360736    // gi0 table [41][768]
#define WS_FLOATS 392224

#define RT 4    // batch rows per block
#define NT 512  // threads per block (8 waves)

__global__ void setup_kernel(const float* __restrict__ Whh0, const float* __restrict__ Wih1,
                             const float* __restrict__ Whh1, const float* __restrict__ Wih2,
                             const float* __restrict__ Whh2, const float* __restrict__ Wproj,
                             const float* __restrict__ Wemb, const float* __restrict__ bemb,
                             const float* __restrict__ Wih0, const float* __restrict__ bih0,
                             float* __restrict__ ws) {
  int idx = blockIdx.x * blockDim.x + threadIdx.x;
  if (idx < 196608) { int o = idx % G1, k = idx / G1; ws[O_HH0 + k*G1 + o] = Whh0[o*H1D + k]; return; }
  idx -= 196608;
  if (idx < 98304)  { int o = idx % G2, k = idx / G2; ws[O_IH1 + k*G2 + o] = Wih1[o*H1D + k]; return; }
  idx -= 98304;
  if (idx < 49152)  { int o = idx % G2, k = idx / G2; ws[O_HH1 + k*G2 + o] = Whh1[o*H2D + k]; return; }
  idx -= 49152;
  if (idx < 12288)  { int o = idx % G3, k = idx / G3; ws[O_IH2 + k*G3 + o] = Wih2[o*H2D + k]; return; }
  idx -= 12288;
  if (idx < 3072)   { int o = idx % G3, k = idx / G3; ws[O_HH2 + k*G3 + o] = Whh2[o*H3D + k]; return; }
  idx -= 3072;
  if (idx < 1312)   { int o = idx % VOC, k = idx / VOC; ws[O_PROJ + k*VOC + o] = Wproj[o*H3D + k]; return; }
  idx -= 1312;
  if (idx < 31488) {
    // gi0 table: exact (f64-accumulated) x@Wih0.T + bih0 per token value.
    int o = idx % G1, v = idx / G1;
    double acc = (double)bih0[o];
    const float* wrow = Wih0 + (size_t)o * H0D;
    for (int k = 0; k < H0D; ++k)
      acc += ((double)Wemb[k*VOC + v] + (double)bemb[k]) * (double)wrow[k];
    ws[O_TAB + v*G1 + o] = (float)acc;
  }
}

__device__ __forceinline__ double sigmd(double x) { return 1.0 / (1.0 + exp(-x)); }

// Union LDS views (lifetimes separated by barriers; audited per-pair below)
#define SCA(kh,r,g,j)   scU[((((kh)*RT+(r))*3+(g))<<8) + (j)]   // [2][RT][3][256] = 6144
#define SCB(sg,r,g,jb)  scU[((((sg)*RT+(r))*3+(g))<<7) + (jb)]  // [4][RT][3][128] = 6144
#define SCC(sc,g,r,jc)  scU[((((sc)*3+(g))*RT+(r))<<5) + (jc)]  // [10][3][RT][32] = 3840

__global__ __launch_bounds__(NT, 2) void gru_persist(
    const float* __restrict__ latent, const int* __restrict__ tgt,
    const float* __restrict__ Winit, const float* __restrict__ binit,
    const float* __restrict__ bhh0,
    const float* __restrict__ bih1, const float* __restrict__ bhh1,
    const float* __restrict__ bih2, const float* __restrict__ bhh2,
    const float* __restrict__ bproj,
    const float* __restrict__ ws, float* __restrict__ out)
{
  const int tid = threadIdx.x;
  const int r0 = blockIdx.x * RT;

  const float* wt_hh0 = ws + O_HH0;
  const float* wt_ih1 = ws + O_IH1;
  const float* wt_hh1 = ws + O_HH1;
  const float* wt_ih2 = ws + O_IH2;
  const float* wt_hh2 = ws + O_HH2;
  const float* wt_proj = ws + O_PROJ;
  const float* tab = ws + O_TAB;

  float* __restrict__ out_logits = out;
  float* __restrict__ out_pred = out + (size_t)BATCH * SEQ * VOC;

  __shared__ float scU[6144];             // 24 KB union: scA / scB / scC
  __shared__ float h0s[RT][H1D];          // 4 KB
  __shared__ float h1s[RT][H2D];          // 2 KB
  __shared__ float h2s[RT][H3D];          // 0.5 KB
  __shared__ int toks[RT];

  // ---- init hidden states: combined = latent @ Winit.T + binit (f64, one-time)
  for (int idx = tid; idx < RT * 416; idx += NT) {
    int r = idx / 416, jj = idx - r * 416;
    const float* lrow = latent + (size_t)(r0 + r) * LAT;
    const float* wrow = Winit + (size_t)jj * LAT;
    double acc = (double)binit[jj];
    for (int k = 0; k < LAT; ++k) acc += (double)lrow[k] * (double)wrow[k];
    float a = (float)acc;
    if (jj < H1D) h0s[r][jj] = a;
    else if (jj < H1D + H2D) h1s[r][jj - H1D] = a;
    else h2s[r][jj - H1D - H2D] = a;
  }
  __syncthreads();

  for (int t = 0; t < SEQ; ++t) {
    if (tid < RT) toks[tid] = (t == 0) ? SOS : tgt[(size_t)(r0 + tid) * SEQ + t];

    // ======== Stage A: GRU0 gh. j = tid&255, K=256 split by kh = tid>>8 ========
    // f32 FMA in chunks of 8, f64 carry per chunk; only one float4 hv[RT] live at a time.
    const int j = tid & 255;
    const int kh = tid >> 8;
    {
      double acc[3][RT];
      #pragma unroll
      for (int g3 = 0; g3 < 3; ++g3)
        #pragma unroll
        for (int r = 0; r < RT; ++r) acc[g3][r] = 0.0;
      const float* __restrict__ wbase = wt_hh0 + j;
      const int k0 = kh * 128;
      for (int kb = k0; kb < k0 + 128; kb += 8) {
        float f[3][RT];
        #pragma unroll
        for (int g3 = 0; g3 < 3; ++g3)
          #pragma unroll
          for (int r = 0; r < RT; ++r) f[g3][r] = 0.f;
        #pragma unroll
        for (int half = 0; half < 2; ++half) {
          float4 hv[RT];
          #pragma unroll
          for (int r = 0; r < RT; ++r) hv[r] = *(const float4*)&h0s[r][kb + 4 * half];
          #pragma unroll
          for (int u = 0; u < 4; ++u) {
            const float* wp = wbase + (size_t)(kb + 4 * half + u) * G1;
            float w0 = wp[0], w1 = wp[256], w2 = wp[512];
            #pragma unroll
            for (int r = 0; r < RT; ++r) {
              float hval = ((const float*)&hv[r])[u];
              f[0][r] = fmaf(hval, w0, f[0][r]);
              f[1][r] = fmaf(hval, w1, f[1][r]);
              f[2][r] = fmaf(hval, w2, f[2][r]);
            }
          }
        }
        #pragma unroll
        for (int g3 = 0; g3 < 3; ++g3)
          #pragma unroll
          for (int r = 0; r < RT; ++r) acc[g3][r] += (double)f[g3][r];
      }
      #pragma unroll
      for (int r = 0; r < RT; ++r) {
        SCA(kh, r, 0, j) = (float)acc[0][r];
        SCA(kh, r, 1, j) = (float)acc[1][r];
        SCA(kh, r, 2, j) = (float)acc[2][r];
      }
    }
    __syncthreads();  // B1: scA partials + toks visible; all h0s dot-reads done
    {
      // pointwise split: kh half owns rows {2kh, 2kh+1}
      const double bR = (double)bhh0[j], bZ = (double)bhh0[256 + j], bN = (double)bhh0[512 + j];
      #pragma unroll
      for (int rr = 0; rr < 2; ++rr) {
        const int r = kh * 2 + rr;
        const float* trow = tab + (size_t)toks[r] * G1;
        double gR = (double)trow[j] + (double)SCA(0, r, 0, j) + (double)SCA(1, r, 0, j) + bR;
        double gZ = (double)trow[256 + j] + (double)SCA(0, r, 1, j) + (double)SCA(1, r, 1, j) + bZ;
        double giN = (double)trow[512 + j];
        double ghN = (double)SCA(0, r, 2, j) + (double)SCA(1, r, 2, j) + bN;
        double rg = sigmd(gR);
        double zg = sigmd(gZ);
        double ng = tanh(fma(rg, ghN, giN));
        h0s[r][j] = (float)((1.0 - zg) * ng + zg * (double)h0s[r][j]);
      }
    }
    __syncthreads();  // B2: h0s new visible; scA free

    // ======== Stage B: GRU1. jb=tid&127; g=tid>>7: g0,g1 = gi1 K-halves (new h0s),
    //                                               g2,g3 = gh1 K-halves (old h1s) ========
    const int jb = tid & 127;
    const int g = tid >> 7;
    {
      double acc[3][RT];
      #pragma unroll
      for (int g3 = 0; g3 < 3; ++g3)
        #pragma unroll
        for (int r = 0; r < RT; ++r) acc[g3][r] = 0.0;
      const float* __restrict__ wbase = (g < 2) ? (wt_ih1 + jb) : (wt_hh1 + jb);
      const int k0 = (g < 2) ? g * 128 : (g - 2) * 64;
      const int kn = (g < 2) ? 128 : 64;
      for (int kb = k0; kb < k0 + kn; kb += 8) {
        float f[3][RT];
        #pragma unroll
        for (int g3 = 0; g3 < 3; ++g3)
          #pragma unroll
          for (int r = 0; r < RT; ++r) f[g3][r] = 0.f;
        #pragma unroll
        for (int half = 0; half < 2; ++half) {
          float4 hv[RT];
          if (g < 2) {
            #pragma unroll
            for (int r = 0; r < RT; ++r) hv[r] = *(const float4*)&h0s[r][kb + 4 * half];
          } else {
            #pragma unroll
            for (int r = 0; r < RT; ++r) hv[r] = *(const float4*)&h1s[r][kb + 4 * half];
          }
          #pragma unroll
          for (int u = 0; u < 4; ++u) {
            const float* wp = wbase + (size_t)(kb + 4 * half + u) * G2;
            float w0 = wp[0], w1 = wp[128], w2 = wp[256];
            #pragma unroll
            for (int r = 0; r < RT; ++r) {
              float hval = ((const float*)&hv[r])[u];
              f[0][r] = fmaf(hval, w0, f[0][r]);
              f[1][r] = fmaf(hval, w1, f[1][r]);
              f[2][r] = fmaf(hval, w2, f[2][r]);
            }
          }
        }
        #pragma unroll
        for (int g3 = 0; g3 < 3; ++g3)
          #pragma unroll
          for (int r = 0; r < RT; ++r) acc[g3][r] += (double)f[g3][r];
      }
      #pragma unroll
      for (int r = 0; r < RT; ++r) {
        SCB(g, r, 0, jb) = (float)acc[0][r];
        SCB(g, r, 1, jb) = (float)acc[1][r];
        SCB(g, r, 2, jb) = (float)acc[2][r];
      }
    }
    __syncthreads();  // B3: scB partials visible; all h0s/h1s dot-reads done
    {
      // pointwise: group g owns row r=g
      const int r = g;
      const double biR = (double)bih1[jb], biZ = (double)bih1[128 + jb], biN = (double)bih1[256 + jb];
      const double bhR = (double)bhh1[jb], bhZ = (double)bhh1[128 + jb], bhN = (double)bhh1[256 + jb];
      double giR = (double)SCB(0, r, 0, jb) + (double)SCB(1, r, 0, jb) + biR;
      double giZ = (double)SCB(0, r, 1, jb) + (double)SCB(1, r, 1, jb) + biZ;
      double giN = (double)SCB(0, r, 2, jb) + (double)SCB(1, r, 2, jb) + biN;
      double ghR = (double)SCB(2, r, 0, jb) + (double)SCB(3, r, 0, jb) + bhR;
      double ghZ = (double)SCB(2, r, 1, jb) + (double)SCB(3, r, 1, jb) + bhZ;
      double ghN = (double)SCB(2, r, 2, jb) + (double)SCB(3, r, 2, jb) + bhN;
      double rg = sigmd(giR + ghR);
      double zg = sigmd(giZ + ghZ);
      double ng = tanh(fma(rg, ghN, giN));
      h1s[r][jb] = (float)((1.0 - zg) * ng + zg * (double)h1s[r][jb]);
    }
    __syncthreads();  // B4: h1s new visible; scB free

    // ======== Stage C: GRU2. jc=tid&31; sc=tid>>5: sc0..7 = gi2 K-slices of 16 (new h1s),
    //                                               sc8,9 = gh2 K-slices of 16 (old h2s) ========
    const int jc = tid & 31;
    const int sc = tid >> 5;  // 0..15
    {
      float f[3][RT];
      #pragma unroll
      for (int g3 = 0; g3 < 3; ++g3)
        #pragma unroll
        for (int r = 0; r < RT; ++r) f[g3][r] = 0.f;
      if (sc < 8) {
        for (int kk = 0; kk < 16; ++kk) {
          int k = sc * 16 + kk;
          const float* wp = wt_ih2 + (size_t)k * G3;
          float w0 = wp[jc], w1 = wp[32 + jc], w2 = wp[64 + jc];
          #pragma unroll
          for (int r = 0; r < RT; ++r) {
            float hval = h1s[r][k];
            f[0][r] = fmaf(hval, w0, f[0][r]);
            f[1][r] = fmaf(hval, w1, f[1][r]);
            f[2][r] = fmaf(hval, w2, f[2][r]);
          }
        }
      } else if (sc < 10) {
        for (int kk = 0; kk < 16; ++kk) {
          int k = (sc - 8) * 16 + kk;
          const float* wp = wt_hh2 + (size_t)k * G3;
          float w0 = wp[jc], w1 = wp[32 + jc], w2 = wp[64 + jc];
          #pragma unroll
          for (int r = 0; r < RT; ++r) {
            float hval = h2s[r][k];
            f[0][r] = fmaf(hval, w0, f[0][r]);
            f[1][r] = fmaf(hval, w1, f[1][r]);
            f[2][r] = fmaf(hval, w2, f[2][r]);
          }
        }
      }
      if (sc < 10) {
        #pragma unroll
        for (int r = 0; r < RT; ++r) {
          SCC(sc, 0, r, jc) = f[0][r];
          SCC(sc, 1, r, jc) = f[1][r];
          SCC(sc, 2, r, jc) = f[2][r];
        }
      }
    }
    __syncthreads();  // B5: scC partials visible; all h1s/h2s dot-reads done
    if (tid < 128) {
      int r = tid >> 5, jj = tid & 31;
      double giR = (double)bih2[jj], giZ = (double)bih2[32 + jj], giN = (double)bih2[64 + jj];
      #pragma unroll
      for (int s = 0; s < 8; ++s) {
        giR += (double)SCC(s, 0, r, jj);
        giZ += (double)SCC(s, 1, r, jj);
        giN += (double)SCC(s, 2, r, jj);
      }
      double ghR = (double)SCC(8, 0, r, jj) + (double)SCC(9, 0, r, jj) + (double)bhh2[jj];
      double ghZ = (double)SCC(8, 1, r, jj) + (double)SCC(9, 1, r, jj) + (double)bhh2[32 + jj];
      double ghN = (double)SCC(8, 2, r, jj) + (double)SCC(9, 2, r, jj) + (double)bhh2[64 + jj];
      double rg = sigmd(giR + ghR);
      double zg = sigmd(giZ + ghZ);
      double ng = tanh(fma(rg, ghN, giN));
      h2s[r][jj] = (float)((1.0 - zg) * ng + zg * (double)h2s[r][jj]);
    }
    __syncthreads();  // B6: h2s new visible; scC free

    // ======== Stage D: projection + wave-shuffle argmax. Wave w = row r, lane = c ========
    if (tid < 4 * 64) {
      const int r = tid >> 6;        // wave index = row
      const int c = tid & 63;        // lane = vocab column (c >= VOC inactive)
      float accf;
      if (c < VOC) {
        double acc = (double)bproj[c];
        #pragma unroll
        for (int k = 0; k < H3D; ++k)
          acc = fma((double)h2s[r][k], (double)wt_proj[k * VOC + c], acc);
        accf = (float)acc;
        out_logits[((size_t)(r0 + r) * SEQ + t) * VOC + c] = accf;
      } else {
        accf = -3.0e38f;
      }
      // 64-lane argmax, np tie-break (first max wins)
      float v = accf;
      int bi = c;
      #pragma unroll
      for (int off = 32; off >= 1; off >>= 1) {
        float ov = __shfl_xor(v, off, 64);
        int oi = __shfl_xor(bi, off, 64);
        if (ov > v || (ov == v && oi < bi)) { v = ov; bi = oi; }
      }
      if (c == 0) out_pred[(size_t)(r0 + r) * SEQ + t] = (float)bi;
    }
    // Hazard audit (6 barriers): scA-read(t, after B1) vs scB-write(t, after B2): B2.
    // scB-read(after B3) vs scC-write(after B4): B4. scC-read(after B5) vs
    // scA-write(t+1, after B6): B6. Stage D h2s-read(t, after B6) vs h2s-write(t+1,
    // after B5(t+1)): B1..B5(t+1). toks-write(t+1, before B1(t+1)) vs toks-read(t,
    // before B2(t)): B2..B6(t).
  }
}

extern "C" void kernel_launch(void* const* d_in, const int* in_sizes, int n_in,
                              void* d_out, int out_size, void* d_ws, size_t ws_size,
                              hipStream_t stream) {
  const float* latent  = (const float*)d_in[0];
  const int*   tgt     = (const int*)d_in[1];
  const float* Wemb    = (const float*)d_in[2];
  const float* bemb    = (const float*)d_in[3];
  const float* Winit   = (const float*)d_in[4];
  const float* binit   = (const float*)d_in[5];
  const float* Wih0    = (const float*)d_in[6];
  const float* Whh0    = (const float*)d_in[7];
  const float* bih0    = (const float*)d_in[8];
  const float* bhh0    = (const float*)d_in[9];
  const float* Wih1    = (const float*)d_in[10];
  const float* Whh1    = (const float*)d_in[11];
  const float* bih1    = (const float*)d_in[12];
  const float* bhh1    = (const float*)d_in[13];
  const float* Wih2    = (const float*)d_in[14];
  const float* Whh2    = (const float*)d_in[15];
  const float* bih2    = (const float*)d_in[16];
  const float* bhh2    = (const float*)d_in[17];
  const float* Wproj   = (const float*)d_in[18];
  const float* bproj   = (const float*)d_in[19];

  float* ws = (float*)d_ws;
  float* out = (float*)d_out;

  int setup_threads = WS_FLOATS;
  int setup_blocks = (setup_threads + 255) / 256;
  setup_kernel<<<setup_blocks, 256, 0, stream>>>(Whh0, Wih1, Whh1, Wih2, Whh2, Wproj,
                                                Wemb, bemb, Wih0, bih0, ws);

  gru_persist<<<BATCH / RT, NT, 0, stream>>>(latent, tgt, Winit, binit,
                                             bhh0, bih1, bhh1, bih2, bhh2, bproj,
                                             ws, out);
}